// Round 5
// baseline (821.789 us; speedup 1.0000x reference)
//
#include <hip/hip_runtime.h>
#include <math.h>

#define N_NODES 50000
#define N_EDGES 800000
#define F_IN    128
#define HID     64
#define HEADS   4
#define HC      256      // HEADS*HID
#define EDIM    9
#define EDIMP   12       // padded (16B-aligned rows)
#define MB      16       // nodes per block in node_transform
#define NSCAN   ((N_NODES + 255) / 256)   // 196

// ---- weight transpose (both mats in one launch): Wt4[kk*256+t] = {W[4kk..4kk+3][t]} ----
__global__ void transpose_w2(const float* __restrict__ Wl, const float* __restrict__ Wr,
                             int K4, float4* __restrict__ Wlt, float4* __restrict__ Wrt) {
    int i = blockIdx.x * 256 + threadIdx.x;
    const int tot = K4 * 256;
    const float* W = (i < tot) ? Wl : Wr;
    float4* Wt = (i < tot) ? Wlt : Wrt;
    if (i >= tot) i -= tot;
    const int t = i & 255, kk = i >> 8;
    float4 v;
    v.x = W[(size_t)(4 * kk + 0) * HC + t];
    v.y = W[(size_t)(4 * kk + 1) * HC + t];
    v.z = W[(size_t)(4 * kk + 2) * HC + t];
    v.w = W[(size_t)(4 * kk + 3) * HC + t];
    Wt[i] = v;
}

// ---------------- node transform: xl = in@Wl+bl, xr = in@Wr+br ----------------
// x-tile loads are block-uniform -> scalarize to s_load (SGPR); no LDS at all.
template<int K>
__global__ __launch_bounds__(256) void node_transform_t(
        const float* __restrict__ in,
        const float4* __restrict__ Wlt, const float* __restrict__ bl,
        const float4* __restrict__ Wrt, const float* __restrict__ br,
        float* __restrict__ xl, float* __restrict__ xr) {
    const int t = threadIdx.x;
    const int node0 = blockIdx.x * MB;
    const float* __restrict__ xp = in + (size_t)node0 * K;   // block-uniform base

    float accl[MB], accr[MB];
    const float bll = bl[t], brr = br[t];
    #pragma unroll
    for (int m = 0; m < MB; ++m) { accl[m] = bll; accr[m] = brr; }

    for (int kk = 0; kk < K / 4; ++kk) {
        const float4 wl = Wlt[kk * 256 + t];
        const float4 wr = Wrt[kk * 256 + t];
        #pragma unroll
        for (int m = 0; m < MB; ++m) {
            const float4 v = *(const float4*)(xp + m * K + kk * 4);  // uniform -> s_load
            accl[m] = fmaf(v.x, wl.x, accl[m]);
            accl[m] = fmaf(v.y, wl.y, accl[m]);
            accl[m] = fmaf(v.z, wl.z, accl[m]);
            accl[m] = fmaf(v.w, wl.w, accl[m]);
            accr[m] = fmaf(v.x, wr.x, accr[m]);
            accr[m] = fmaf(v.y, wr.y, accr[m]);
            accr[m] = fmaf(v.z, wr.z, accr[m]);
            accr[m] = fmaf(v.w, wr.w, accr[m]);
        }
    }
    #pragma unroll
    for (int m = 0; m < MB; ++m) {
        xl[(size_t)(node0 + m) * HC + t] = accl[m];
        xr[(size_t)(node0 + m) * HC + t] = accr[m];
    }
}

// ---------------- CSR build (once per launch) ----------------
__global__ void zero_counts(int* __restrict__ counts, int* __restrict__ cursor) {
    const int i = blockIdx.x * blockDim.x + threadIdx.x;
    if (i < N_NODES) { counts[i] = 0; cursor[i] = 0; }
}

__global__ void count_deg(const int* __restrict__ dst, int* __restrict__ counts) {
    const int e = blockIdx.x * blockDim.x + threadIdx.x;
    if (e < N_EDGES) atomicAdd(&counts[dst[e]], 1);
}

__global__ void scanA(const int* __restrict__ counts, int* __restrict__ bsum) {
    __shared__ int s[256];
    const int t = threadIdx.x;
    const int i = blockIdx.x * 256 + t;
    s[t] = (i < N_NODES) ? counts[i] : 0;
    __syncthreads();
    for (int st = 128; st > 0; st >>= 1) {
        if (t < st) s[t] += s[t + st];
        __syncthreads();
    }
    if (t == 0) bsum[blockIdx.x] = s[0];
}

__global__ void scanB(const int* __restrict__ bsum, int* __restrict__ boff) {
    __shared__ int s[256];
    const int t = threadIdx.x;
    const int orig = (t < NSCAN) ? bsum[t] : 0;
    s[t] = orig;
    __syncthreads();
    for (int st = 1; st < 256; st <<= 1) {
        int v = (t >= st) ? s[t - st] : 0;
        __syncthreads();
        s[t] += v;
        __syncthreads();
    }
    if (t < NSCAN) boff[t] = s[t] - orig;   // exclusive
}

__global__ void scanC(const int* __restrict__ counts, const int* __restrict__ boff,
                      int* __restrict__ offs) {
    __shared__ int s[256];
    const int t = threadIdx.x;
    const int i = blockIdx.x * 256 + t;
    const int orig = (i < N_NODES) ? counts[i] : 0;
    s[t] = orig;
    __syncthreads();
    for (int st = 1; st < 256; st <<= 1) {
        int v = (t >= st) ? s[t - st] : 0;
        __syncthreads();
        s[t] += v;
        __syncthreads();
    }
    if (i < N_NODES) offs[i] = boff[blockIdx.x] + s[t] - orig;  // exclusive
    if (i == 0) offs[N_NODES] = N_EDGES;
}

__global__ void fill_csr(const int* __restrict__ src, const int* __restrict__ dst,
                         const int* __restrict__ offs, int* __restrict__ cursor,
                         int* __restrict__ srcp, int* __restrict__ perm) {
    const int e = blockIdx.x * blockDim.x + threadIdx.x;
    if (e >= N_EDGES) return;
    const int d = dst[e];
    const int pos = offs[d] + atomicAdd(&cursor[d], 1);
    srcp[pos] = src[e];
    perm[pos] = e;
}

// permute + pad edge_attr into CSR order: eap[j][0..8] = ea[perm[j]][0..8], [9..11]=0
__global__ void permute_ea(const float* __restrict__ ea, const int* __restrict__ perm,
                           float* __restrict__ eap) {
    const int j = blockIdx.x * blockDim.x + threadIdx.x;
    if (j >= N_EDGES) return;
    const int e = perm[j];
    float v[EDIMP];
    #pragma unroll
    for (int u = 0; u < EDIM; ++u) v[u] = ea[(size_t)e * EDIM + u];
    #pragma unroll
    for (int u = EDIM; u < EDIMP; ++u) v[u] = 0.f;
    float4* o = (float4*)(eap + (size_t)j * EDIMP);
    o[0] = *(float4*)(v);
    o[1] = *(float4*)(v + 4);
    o[2] = *(float4*)(v + 8);
}

// ---------------- fused per-dst-node edge kernel ----------------
// 256-thr blocks, 4 independent waves = 4 nodes/block. Online softmax per node.
template<int PERMUTED>
__global__ __launch_bounds__(256) void fused_edge(
        const float* __restrict__ xl, const float* __restrict__ xr,
        const float* __restrict__ eap, const float* __restrict__ ea,
        const int* __restrict__ perm,
        const int* __restrict__ offs, const int* __restrict__ srcp,
        const float* __restrict__ We, const float* __restrict__ att,
        const float* __restrict__ bias, const float* __restrict__ gates,
        float* __restrict__ h, float* __restrict__ hact, int layer) {
    const int d = blockIdx.x * 4 + (threadIdx.x >> 6);
    const int lane = threadIdx.x & 63;
    const int c0 = lane * 4;

    const float4 vxr  = *(const float4*)(xr + (size_t)d * HC + c0);
    const float4 watt = *(const float4*)(att + c0);
    float4 wWe[EDIM];
    #pragma unroll
    for (int u = 0; u < EDIM; ++u) wWe[u] = *(const float4*)(We + u * HC + c0);

    float m = -INFINITY, den = 0.f;
    float4 acc = {0.f, 0.f, 0.f, 0.f};

    const int jb = offs[d], je = offs[d + 1];

    float4 aA, aB, eA0, eA1, eA2, eB0, eB1, eB2;

    auto loadE = [&](int j, float4& a, float4& f0, float4& f1, float4& f2) {
        const int s = srcp[j];
        a = *(const float4*)(xl + (size_t)s * HC + c0);
        if (PERMUTED) {
            const float4* ep = (const float4*)(eap + (size_t)j * EDIMP);
            f0 = ep[0]; f1 = ep[1]; f2 = ep[2];
        } else {
            const float* ep = ea + (size_t)perm[j] * EDIM;
            f0.x = ep[0]; f0.y = ep[1]; f0.z = ep[2]; f0.w = ep[3];
            f1.x = ep[4]; f1.y = ep[5]; f1.z = ep[6]; f1.w = ep[7];
            f2.x = ep[8]; f2.y = 0.f; f2.z = 0.f; f2.w = 0.f;
        }
    };

    auto compute = [&](const float4& a, const float4& f0, const float4& f1, const float4& f2) {
        const float ef[EDIM] = {f0.x, f0.y, f0.z, f0.w, f1.x, f1.y, f1.z, f1.w, f2.x};
        float4 t;
        t.x = a.x + vxr.x; t.y = a.y + vxr.y; t.z = a.z + vxr.z; t.w = a.w + vxr.w;
        #pragma unroll
        for (int u = 0; u < EDIM; ++u) {
            t.x = fmaf(ef[u], wWe[u].x, t.x);
            t.y = fmaf(ef[u], wWe[u].y, t.y);
            t.z = fmaf(ef[u], wWe[u].z, t.z);
            t.w = fmaf(ef[u], wWe[u].w, t.w);
        }
        t.x = fmaxf(t.x, 0.2f * t.x);
        t.y = fmaxf(t.y, 0.2f * t.y);
        t.z = fmaxf(t.z, 0.2f * t.z);
        t.w = fmaxf(t.w, 0.2f * t.w);
        float l = fmaf(t.x, watt.x, fmaf(t.y, watt.y, fmaf(t.z, watt.z, t.w * watt.w)));
        l += __shfl_xor(l, 1, 64);
        l += __shfl_xor(l, 2, 64);
        l += __shfl_xor(l, 4, 64);
        l += __shfl_xor(l, 8, 64);
        if (__ballot(l > m)) {          // some head has a new max -> rescale
            const float nm = fmaxf(m, l);
            const float sc = __expf(m - nm);
            const float p  = __expf(l - nm);
            den = fmaf(den, sc, p);
            acc.x = fmaf(acc.x, sc, p * a.x);
            acc.y = fmaf(acc.y, sc, p * a.y);
            acc.z = fmaf(acc.z, sc, p * a.z);
            acc.w = fmaf(acc.w, sc, p * a.w);
            m = nm;
        } else {                        // defer path: max unchanged
            const float p = __expf(l - m);
            den += p;
            acc.x = fmaf(p, a.x, acc.x);
            acc.y = fmaf(p, a.y, acc.y);
            acc.z = fmaf(p, a.z, acc.z);
            acc.w = fmaf(p, a.w, acc.w);
        }
    };

    int j = jb;
    if (j < je) loadE(j, aA, eA0, eA1, eA2);
    while (j + 1 < je) {
        loadE(j + 1, aB, eB0, eB1, eB2);
        compute(aA, eA0, eA1, eA2);
        if (j + 2 < je) {
            loadE(j + 2, aA, eA0, eA1, eA2);
            compute(aB, eB0, eB1, eB2);
        } else {
            compute(aB, eB0, eB1, eB2);
        }
        j += 2;
    }
    if (j < je) compute(aA, eA0, eA1, eA2);

    const float inv = 1.f / (den + 1e-16f);
    float4 v;
    v.x = acc.x * inv; v.y = acc.y * inv; v.z = acc.z * inv; v.w = acc.w * inv;
    v.x += __shfl_xor(v.x, 16, 64);  v.x += __shfl_xor(v.x, 32, 64);
    v.y += __shfl_xor(v.y, 16, 64);  v.y += __shfl_xor(v.y, 32, 64);
    v.z += __shfl_xor(v.z, 16, 64);  v.z += __shfl_xor(v.z, 32, 64);
    v.w += __shfl_xor(v.w, 16, 64);  v.w += __shfl_xor(v.w, 32, 64);

    if (lane < 16) {
        const int c = lane * 4;
        float4 outv;
        outv.x = fmaf(0.25f, v.x, bias[c + 0]);
        outv.y = fmaf(0.25f, v.y, bias[c + 1]);
        outv.z = fmaf(0.25f, v.z, bias[c + 2]);
        outv.w = fmaf(0.25f, v.w, bias[c + 3]);
        if (layer > 0) {
            const float g = 1.f / (1.f + __expf(-gates[layer - 1]));
            float4 pv = *(const float4*)(h + (size_t)d * HID + c);
            pv.x = fmaxf(pv.x, 0.01f * pv.x);
            pv.y = fmaxf(pv.y, 0.01f * pv.y);
            pv.z = fmaxf(pv.z, 0.01f * pv.z);
            pv.w = fmaxf(pv.w, 0.01f * pv.w);
            outv.x = g * outv.x + (1.f - g) * pv.x;
            outv.y = g * outv.y + (1.f - g) * pv.y;
            outv.z = g * outv.z + (1.f - g) * pv.z;
            outv.w = g * outv.w + (1.f - g) * pv.w;
        }
        *(float4*)(h + (size_t)d * HID + c) = outv;
        if (layer < 2) {   // pre-activated copy for next layer's node_transform
            float4 av;
            av.x = fmaxf(outv.x, 0.01f * outv.x);
            av.y = fmaxf(outv.y, 0.01f * outv.y);
            av.z = fmaxf(outv.z, 0.01f * outv.z);
            av.w = fmaxf(outv.w, 0.01f * outv.w);
            *(float4*)(hact + (size_t)d * HID + c) = av;
        }
    }
}

extern "C" void kernel_launch(void* const* d_in, const int* in_sizes, int n_in,
                              void* d_out, int out_size, void* d_ws, size_t ws_size,
                              hipStream_t stream) {
    const float* x     = (const float*)d_in[0];
    const float* ea    = (const float*)d_in[1];
    const float* iWl   = (const float*)d_in[2];
    const float* ibl   = (const float*)d_in[3];
    const float* iWr   = (const float*)d_in[4];
    const float* ibr   = (const float*)d_in[5];
    const float* iWe   = (const float*)d_in[6];
    const float* iatt  = (const float*)d_in[7];
    const float* ibias = (const float*)d_in[8];
    const float* Wl    = (const float*)d_in[9];
    const float* bl    = (const float*)d_in[10];
    const float* Wr    = (const float*)d_in[11];
    const float* br    = (const float*)d_in[12];
    const float* We    = (const float*)d_in[13];
    const float* att   = (const float*)d_in[14];
    const float* bias  = (const float*)d_in[15];
    const float* gates = (const float*)d_in[16];
    const int*   ei    = (const int*)d_in[17];
    const int* src = ei;
    const int* dst = ei + N_EDGES;

    float* ws = (float*)d_ws;
    float*  xl   = ws;                                    // 12.8M floats
    float*  xr   = xl + (size_t)N_NODES * HC;             // 12.8M
    float*  hact = xr + (size_t)N_NODES * HC;             // 3.2M
    float4* wlt  = (float4*)(hact + (size_t)N_NODES * HID);  // 32768 f4
    float4* wrt  = wlt + 32768;                           // 32768 f4
    float*  eap  = (float*)(wrt + 32768);                 // 9.6M floats
    int* ibase  = (int*)(eap + (size_t)N_EDGES * EDIMP);
    int* counts = ibase;                                  // 50000
    int* cursor = counts + N_NODES;                       // 50000
    int* offs   = cursor + N_NODES;                       // 50001
    int* bsum   = offs + N_NODES + 1;                     // 256
    int* boff   = bsum + 256;                             // 256
    int* srcp   = boff + 256;                             // 800000
    int* perm   = srcp + N_EDGES;                         // 800000
    float* h    = (float*)d_out;

    const size_t need = (size_t)((char*)(perm + N_EDGES) - (char*)d_ws);
    const int permuted = (ws_size >= need) ? 1 : 0;

    zero_counts<<<(N_NODES + 255) / 256, 256, 0, stream>>>(counts, cursor);
    count_deg<<<(N_EDGES + 255) / 256, 256, 0, stream>>>(dst, counts);
    scanA<<<NSCAN, 256, 0, stream>>>(counts, bsum);
    scanB<<<1, 256, 0, stream>>>(bsum, boff);
    scanC<<<NSCAN, 256, 0, stream>>>(counts, boff, offs);
    fill_csr<<<(N_EDGES + 255) / 256, 256, 0, stream>>>(src, dst, offs, cursor, srcp, perm);
    if (permuted)
        permute_ea<<<(N_EDGES + 255) / 256, 256, 0, stream>>>(ea, perm, eap);

    for (int layer = 0; layer < 3; ++layer) {
        const int    K     = (layer == 0) ? F_IN : HID;
        const float* in_   = (layer == 0) ? x : hact;
        const float* wl_   = (layer == 0) ? iWl   : Wl   + (size_t)(layer - 1) * HID * HC;
        const float* bl_   = (layer == 0) ? ibl   : bl   + (size_t)(layer - 1) * HC;
        const float* wr_   = (layer == 0) ? iWr   : Wr   + (size_t)(layer - 1) * HID * HC;
        const float* br_   = (layer == 0) ? ibr   : br   + (size_t)(layer - 1) * HC;
        const float* we_   = (layer == 0) ? iWe   : We   + (size_t)(layer - 1) * EDIM * HC;
        const float* att_  = (layer == 0) ? iatt  : att  + (size_t)(layer - 1) * HC;
        const float* bias_ = (layer == 0) ? ibias : bias + (size_t)(layer - 1) * HID;

        transpose_w2<<<2 * (K / 4), 256, 0, stream>>>(wl_, wr_, K / 4, wlt, wrt);
        if (K == F_IN)
            node_transform_t<F_IN><<<N_NODES / MB, 256, 0, stream>>>(in_, wlt, bl_, wrt, br_, xl, xr);
        else
            node_transform_t<HID><<<N_NODES / MB, 256, 0, stream>>>(in_, wlt, bl_, wrt, br_, xl, xr);

        if (permuted)
            fused_edge<1><<<N_NODES / 4, 256, 0, stream>>>(xl, xr, eap, ea, perm, offs, srcp,
                                                           we_, att_, bias_, gates, h, hact, layer);
        else
            fused_edge<0><<<N_NODES / 4, 256, 0, stream>>>(xl, xr, eap, ea, perm, offs, srcp,
                                                           we_, att_, bias_, gates, h, hact, layer);
    }
}

// Round 6
// 697.827 us; speedup vs baseline: 1.1776x; 1.1776x over previous
//
#include <hip/hip_runtime.h>
#include <math.h>

#define N_NODES 50000
#define N_EDGES 800000
#define F_IN    128
#define HID     64
#define HEADS   4
#define HC      256      // HEADS*HID
#define EDIM    9
#define EDIMP   12       // padded (16B-aligned rows)
#define MB      16       // nodes per block in node_transform
#define NSCAN   ((N_NODES + 255) / 256)   // 196

// ---- weight transpose (both mats in one launch): Wt4[kk*256+t] = {W[4kk..4kk+3][t]} ----
__global__ void transpose_w2(const float* __restrict__ Wl, const float* __restrict__ Wr,
                             int K4, float4* __restrict__ Wlt, float4* __restrict__ Wrt) {
    int i = blockIdx.x * 256 + threadIdx.x;
    const int tot = K4 * 256;
    const float* W = (i < tot) ? Wl : Wr;
    float4* Wt = (i < tot) ? Wlt : Wrt;
    if (i >= tot) i -= tot;
    const int t = i & 255, kk = i >> 8;
    float4 v;
    v.x = W[(size_t)(4 * kk + 0) * HC + t];
    v.y = W[(size_t)(4 * kk + 1) * HC + t];
    v.z = W[(size_t)(4 * kk + 2) * HC + t];
    v.w = W[(size_t)(4 * kk + 3) * HC + t];
    Wt[i] = v;
}

// ---------------- node transform: xl = in@Wl+bl, xr = in@Wr+br ----------------
// x-tile loads are block-uniform -> scalarize to s_load (SGPR); no LDS at all.
template<int K>
__global__ __launch_bounds__(256) void node_transform_t(
        const float* __restrict__ in,
        const float4* __restrict__ Wlt, const float* __restrict__ bl,
        const float4* __restrict__ Wrt, const float* __restrict__ br,
        float* __restrict__ xl, float* __restrict__ xr) {
    const int t = threadIdx.x;
    const int node0 = blockIdx.x * MB;
    const float* __restrict__ xp = in + (size_t)node0 * K;   // block-uniform base

    float accl[MB], accr[MB];
    const float bll = bl[t], brr = br[t];
    #pragma unroll
    for (int m = 0; m < MB; ++m) { accl[m] = bll; accr[m] = brr; }

    for (int kk = 0; kk < K / 4; ++kk) {
        const float4 wl = Wlt[kk * 256 + t];
        const float4 wr = Wrt[kk * 256 + t];
        #pragma unroll
        for (int m = 0; m < MB; ++m) {
            const float4 v = *(const float4*)(xp + m * K + kk * 4);  // uniform -> s_load
            accl[m] = fmaf(v.x, wl.x, accl[m]);
            accl[m] = fmaf(v.y, wl.y, accl[m]);
            accl[m] = fmaf(v.z, wl.z, accl[m]);
            accl[m] = fmaf(v.w, wl.w, accl[m]);
            accr[m] = fmaf(v.x, wr.x, accr[m]);
            accr[m] = fmaf(v.y, wr.y, accr[m]);
            accr[m] = fmaf(v.z, wr.z, accr[m]);
            accr[m] = fmaf(v.w, wr.w, accr[m]);
        }
    }
    #pragma unroll
    for (int m = 0; m < MB; ++m) {
        xl[(size_t)(node0 + m) * HC + t] = accl[m];
        xr[(size_t)(node0 + m) * HC + t] = accr[m];
    }
}

// ---------------- CSR build (once per launch) ----------------
__global__ void zero_counts(int* __restrict__ counts, int* __restrict__ cursor) {
    const int i = blockIdx.x * blockDim.x + threadIdx.x;
    if (i < N_NODES) { counts[i] = 0; cursor[i] = 0; }
}

__global__ void count_deg(const int* __restrict__ dst, int* __restrict__ counts) {
    const int e = blockIdx.x * blockDim.x + threadIdx.x;
    if (e < N_EDGES) atomicAdd(&counts[dst[e]], 1);
}

__global__ void scanA(const int* __restrict__ counts, int* __restrict__ bsum) {
    __shared__ int s[256];
    const int t = threadIdx.x;
    const int i = blockIdx.x * 256 + t;
    s[t] = (i < N_NODES) ? counts[i] : 0;
    __syncthreads();
    for (int st = 128; st > 0; st >>= 1) {
        if (t < st) s[t] += s[t + st];
        __syncthreads();
    }
    if (t == 0) bsum[blockIdx.x] = s[0];
}

__global__ void scanB(const int* __restrict__ bsum, int* __restrict__ boff) {
    __shared__ int s[256];
    const int t = threadIdx.x;
    const int orig = (t < NSCAN) ? bsum[t] : 0;
    s[t] = orig;
    __syncthreads();
    for (int st = 1; st < 256; st <<= 1) {
        int v = (t >= st) ? s[t - st] : 0;
        __syncthreads();
        s[t] += v;
        __syncthreads();
    }
    if (t < NSCAN) boff[t] = s[t] - orig;   // exclusive
}

__global__ void scanC(const int* __restrict__ counts, const int* __restrict__ boff,
                      int* __restrict__ offs) {
    __shared__ int s[256];
    const int t = threadIdx.x;
    const int i = blockIdx.x * 256 + t;
    const int orig = (i < N_NODES) ? counts[i] : 0;
    s[t] = orig;
    __syncthreads();
    for (int st = 1; st < 256; st <<= 1) {
        int v = (t >= st) ? s[t - st] : 0;
        __syncthreads();
        s[t] += v;
        __syncthreads();
    }
    if (i < N_NODES) offs[i] = boff[blockIdx.x] + s[t] - orig;  // exclusive
    if (i == 0) offs[N_NODES] = N_EDGES;
}

__global__ void fill_csr(const int* __restrict__ src, const int* __restrict__ dst,
                         const int* __restrict__ offs, int* __restrict__ cursor,
                         int* __restrict__ srcp, int* __restrict__ perm) {
    const int e = blockIdx.x * blockDim.x + threadIdx.x;
    if (e >= N_EDGES) return;
    const int d = dst[e];
    const int pos = offs[d] + atomicAdd(&cursor[d], 1);
    srcp[pos] = src[e];
    perm[pos] = e;
}

// permute + pad edge_attr into CSR order: eap[j][0..8] = ea[perm[j]][0..8], [9..11]=0
__global__ void permute_ea(const float* __restrict__ ea, const int* __restrict__ perm,
                           float* __restrict__ eap) {
    const int j = blockIdx.x * blockDim.x + threadIdx.x;
    if (j >= N_EDGES) return;
    const int e = perm[j];
    float v[EDIMP];
    #pragma unroll
    for (int u = 0; u < EDIM; ++u) v[u] = ea[(size_t)e * EDIM + u];
    #pragma unroll
    for (int u = EDIM; u < EDIMP; ++u) v[u] = 0.f;
    float4* o = (float4*)(eap + (size_t)j * EDIMP);
    o[0] = *(float4*)(v);
    o[1] = *(float4*)(v + 4);
    o[2] = *(float4*)(v + 8);
}

// ---------------- fused per-dst-node edge kernel ----------------
// One wave (64-thr block) per destination node; online softmax over in-edges.
// Pair-wise load/compute: 2 outstanding gathers, no register rotation.
template<int PERMUTED>
__global__ __launch_bounds__(64) void fused_edge(
        const float* __restrict__ xl, const float* __restrict__ xr,
        const float* __restrict__ eap, const float* __restrict__ ea,
        const int* __restrict__ perm,
        const int* __restrict__ offs, const int* __restrict__ srcp,
        const float* __restrict__ We, const float* __restrict__ att,
        const float* __restrict__ bias, const float* __restrict__ gates,
        float* __restrict__ h, float* __restrict__ hact, int layer) {
    const int d = blockIdx.x;
    const int lane = threadIdx.x;
    const int c0 = lane * 4;

    const float4 vxr  = *(const float4*)(xr + (size_t)d * HC + c0);
    const float4 watt = *(const float4*)(att + c0);
    float4 wWe[EDIM];
    #pragma unroll
    for (int u = 0; u < EDIM; ++u) wWe[u] = *(const float4*)(We + u * HC + c0);

    float m = -INFINITY, den = 0.f;
    float4 acc = {0.f, 0.f, 0.f, 0.f};

    const int jb = offs[d], je = offs[d + 1];

    float4 aA, aB, eA0, eA1, eA2, eB0, eB1, eB2;

    auto loadE = [&](int j, float4& a, float4& f0, float4& f1, float4& f2) {
        const int s = srcp[j];
        a = *(const float4*)(xl + (size_t)s * HC + c0);
        if (PERMUTED) {
            const float4* ep = (const float4*)(eap + (size_t)j * EDIMP);
            f0 = ep[0]; f1 = ep[1]; f2 = ep[2];
        } else {
            const float* ep = ea + (size_t)perm[j] * EDIM;
            f0.x = ep[0]; f0.y = ep[1]; f0.z = ep[2]; f0.w = ep[3];
            f1.x = ep[4]; f1.y = ep[5]; f1.z = ep[6]; f1.w = ep[7];
            f2.x = ep[8]; f2.y = 0.f; f2.z = 0.f; f2.w = 0.f;
        }
    };

    auto compute = [&](const float4& a, const float4& f0, const float4& f1, const float4& f2) {
        float4 t;
        t.x = a.x + vxr.x; t.y = a.y + vxr.y; t.z = a.z + vxr.z; t.w = a.w + vxr.w;
        t.x = fmaf(f0.x, wWe[0].x, t.x); t.y = fmaf(f0.x, wWe[0].y, t.y);
        t.z = fmaf(f0.x, wWe[0].z, t.z); t.w = fmaf(f0.x, wWe[0].w, t.w);
        t.x = fmaf(f0.y, wWe[1].x, t.x); t.y = fmaf(f0.y, wWe[1].y, t.y);
        t.z = fmaf(f0.y, wWe[1].z, t.z); t.w = fmaf(f0.y, wWe[1].w, t.w);
        t.x = fmaf(f0.z, wWe[2].x, t.x); t.y = fmaf(f0.z, wWe[2].y, t.y);
        t.z = fmaf(f0.z, wWe[2].z, t.z); t.w = fmaf(f0.z, wWe[2].w, t.w);
        t.x = fmaf(f0.w, wWe[3].x, t.x); t.y = fmaf(f0.w, wWe[3].y, t.y);
        t.z = fmaf(f0.w, wWe[3].z, t.z); t.w = fmaf(f0.w, wWe[3].w, t.w);
        t.x = fmaf(f1.x, wWe[4].x, t.x); t.y = fmaf(f1.x, wWe[4].y, t.y);
        t.z = fmaf(f1.x, wWe[4].z, t.z); t.w = fmaf(f1.x, wWe[4].w, t.w);
        t.x = fmaf(f1.y, wWe[5].x, t.x); t.y = fmaf(f1.y, wWe[5].y, t.y);
        t.z = fmaf(f1.y, wWe[5].z, t.z); t.w = fmaf(f1.y, wWe[5].w, t.w);
        t.x = fmaf(f1.z, wWe[6].x, t.x); t.y = fmaf(f1.z, wWe[6].y, t.y);
        t.z = fmaf(f1.z, wWe[6].z, t.z); t.w = fmaf(f1.z, wWe[6].w, t.w);
        t.x = fmaf(f1.w, wWe[7].x, t.x); t.y = fmaf(f1.w, wWe[7].y, t.y);
        t.z = fmaf(f1.w, wWe[7].z, t.z); t.w = fmaf(f1.w, wWe[7].w, t.w);
        t.x = fmaf(f2.x, wWe[8].x, t.x); t.y = fmaf(f2.x, wWe[8].y, t.y);
        t.z = fmaf(f2.x, wWe[8].z, t.z); t.w = fmaf(f2.x, wWe[8].w, t.w);
        t.x = fmaxf(t.x, 0.2f * t.x);
        t.y = fmaxf(t.y, 0.2f * t.y);
        t.z = fmaxf(t.z, 0.2f * t.z);
        t.w = fmaxf(t.w, 0.2f * t.w);
        float l = fmaf(t.x, watt.x, fmaf(t.y, watt.y, fmaf(t.z, watt.z, t.w * watt.w)));
        l += __shfl_xor(l, 1, 64);
        l += __shfl_xor(l, 2, 64);
        l += __shfl_xor(l, 4, 64);
        l += __shfl_xor(l, 8, 64);
        if (__ballot(l > m)) {          // some head has a new max -> rescale
            const float nm = fmaxf(m, l);
            const float sc = __expf(m - nm);
            const float p  = __expf(l - nm);
            den = fmaf(den, sc, p);
            acc.x = fmaf(acc.x, sc, p * a.x);
            acc.y = fmaf(acc.y, sc, p * a.y);
            acc.z = fmaf(acc.z, sc, p * a.z);
            acc.w = fmaf(acc.w, sc, p * a.w);
            m = nm;
        } else {                        // defer path: max unchanged
            const float p = __expf(l - m);
            den += p;
            acc.x = fmaf(p, a.x, acc.x);
            acc.y = fmaf(p, a.y, acc.y);
            acc.z = fmaf(p, a.z, acc.z);
            acc.w = fmaf(p, a.w, acc.w);
        }
    };

    int j = jb;
    for (; j + 2 <= je; j += 2) {
        loadE(j, aA, eA0, eA1, eA2);
        loadE(j + 1, aB, eB0, eB1, eB2);
        compute(aA, eA0, eA1, eA2);
        compute(aB, eB0, eB1, eB2);
    }
    if (j < je) {
        loadE(j, aA, eA0, eA1, eA2);
        compute(aA, eA0, eA1, eA2);
    }

    const float inv = 1.f / (den + 1e-16f);
    float4 v;
    v.x = acc.x * inv; v.y = acc.y * inv; v.z = acc.z * inv; v.w = acc.w * inv;
    v.x += __shfl_xor(v.x, 16, 64);  v.x += __shfl_xor(v.x, 32, 64);
    v.y += __shfl_xor(v.y, 16, 64);  v.y += __shfl_xor(v.y, 32, 64);
    v.z += __shfl_xor(v.z, 16, 64);  v.z += __shfl_xor(v.z, 32, 64);
    v.w += __shfl_xor(v.w, 16, 64);  v.w += __shfl_xor(v.w, 32, 64);

    if (lane < 16) {
        const int c = lane * 4;
        float4 outv;
        outv.x = fmaf(0.25f, v.x, bias[c + 0]);
        outv.y = fmaf(0.25f, v.y, bias[c + 1]);
        outv.z = fmaf(0.25f, v.z, bias[c + 2]);
        outv.w = fmaf(0.25f, v.w, bias[c + 3]);
        if (layer > 0) {
            const float g = 1.f / (1.f + __expf(-gates[layer - 1]));
            float4 pv = *(const float4*)(h + (size_t)d * HID + c);
            pv.x = fmaxf(pv.x, 0.01f * pv.x);
            pv.y = fmaxf(pv.y, 0.01f * pv.y);
            pv.z = fmaxf(pv.z, 0.01f * pv.z);
            pv.w = fmaxf(pv.w, 0.01f * pv.w);
            outv.x = g * outv.x + (1.f - g) * pv.x;
            outv.y = g * outv.y + (1.f - g) * pv.y;
            outv.z = g * outv.z + (1.f - g) * pv.z;
            outv.w = g * outv.w + (1.f - g) * pv.w;
        }
        *(float4*)(h + (size_t)d * HID + c) = outv;
        if (layer < 2) {   // pre-activated copy for next layer's node_transform
            float4 av;
            av.x = fmaxf(outv.x, 0.01f * outv.x);
            av.y = fmaxf(outv.y, 0.01f * outv.y);
            av.z = fmaxf(outv.z, 0.01f * outv.z);
            av.w = fmaxf(outv.w, 0.01f * outv.w);
            *(float4*)(hact + (size_t)d * HID + c) = av;
        }
    }
}

extern "C" void kernel_launch(void* const* d_in, const int* in_sizes, int n_in,
                              void* d_out, int out_size, void* d_ws, size_t ws_size,
                              hipStream_t stream) {
    const float* x     = (const float*)d_in[0];
    const float* ea    = (const float*)d_in[1];
    const float* iWl   = (const float*)d_in[2];
    const float* ibl   = (const float*)d_in[3];
    const float* iWr   = (const float*)d_in[4];
    const float* ibr   = (const float*)d_in[5];
    const float* iWe   = (const float*)d_in[6];
    const float* iatt  = (const float*)d_in[7];
    const float* ibias = (const float*)d_in[8];
    const float* Wl    = (const float*)d_in[9];
    const float* bl    = (const float*)d_in[10];
    const float* Wr    = (const float*)d_in[11];
    const float* br    = (const float*)d_in[12];
    const float* We    = (const float*)d_in[13];
    const float* att   = (const float*)d_in[14];
    const float* bias  = (const float*)d_in[15];
    const float* gates = (const float*)d_in[16];
    const int*   ei    = (const int*)d_in[17];
    const int* src = ei;
    const int* dst = ei + N_EDGES;

    float* ws = (float*)d_ws;
    float*  xl   = ws;                                    // 12.8M floats
    float*  xr   = xl + (size_t)N_NODES * HC;             // 12.8M
    float*  hact = xr + (size_t)N_NODES * HC;             // 3.2M
    float4* wlt  = (float4*)(hact + (size_t)N_NODES * HID);  // 32768 f4
    float4* wrt  = wlt + 32768;                           // 32768 f4
    float*  eap  = (float*)(wrt + 32768);                 // 9.6M floats
    int* ibase  = (int*)(eap + (size_t)N_EDGES * EDIMP);
    int* counts = ibase;                                  // 50000
    int* cursor = counts + N_NODES;                       // 50000
    int* offs   = cursor + N_NODES;                       // 50001
    int* bsum   = offs + N_NODES + 1;                     // 256
    int* boff   = bsum + 256;                             // 256
    int* srcp   = boff + 256;                             // 800000
    int* perm   = srcp + N_EDGES;                         // 800000
    float* h    = (float*)d_out;

    const size_t need = (size_t)((char*)(perm + N_EDGES) - (char*)d_ws);
    const int permuted = (ws_size >= need) ? 1 : 0;

    zero_counts<<<(N_NODES + 255) / 256, 256, 0, stream>>>(counts, cursor);
    count_deg<<<(N_EDGES + 255) / 256, 256, 0, stream>>>(dst, counts);
    scanA<<<NSCAN, 256, 0, stream>>>(counts, bsum);
    scanB<<<1, 256, 0, stream>>>(bsum, boff);
    scanC<<<NSCAN, 256, 0, stream>>>(counts, boff, offs);
    fill_csr<<<(N_EDGES + 255) / 256, 256, 0, stream>>>(src, dst, offs, cursor, srcp, perm);
    if (permuted)
        permute_ea<<<(N_EDGES + 255) / 256, 256, 0, stream>>>(ea, perm, eap);

    for (int layer = 0; layer < 3; ++layer) {
        const int    K     = (layer == 0) ? F_IN : HID;
        const float* in_   = (layer == 0) ? x : hact;
        const float* wl_   = (layer == 0) ? iWl   : Wl   + (size_t)(layer - 1) * HID * HC;
        const float* bl_   = (layer == 0) ? ibl   : bl   + (size_t)(layer - 1) * HC;
        const float* wr_   = (layer == 0) ? iWr   : Wr   + (size_t)(layer - 1) * HID * HC;
        const float* br_   = (layer == 0) ? ibr   : br   + (size_t)(layer - 1) * HC;
        const float* we_   = (layer == 0) ? iWe   : We   + (size_t)(layer - 1) * EDIM * HC;
        const float* att_  = (layer == 0) ? iatt  : att  + (size_t)(layer - 1) * HC;
        const float* bias_ = (layer == 0) ? ibias : bias + (size_t)(layer - 1) * HID;

        transpose_w2<<<2 * (K / 4), 256, 0, stream>>>(wl_, wr_, K / 4, wlt, wrt);
        if (K == F_IN)
            node_transform_t<F_IN><<<N_NODES / MB, 256, 0, stream>>>(in_, wlt, bl_, wrt, br_, xl, xr);
        else
            node_transform_t<HID><<<N_NODES / MB, 256, 0, stream>>>(in_, wlt, bl_, wrt, br_, xl, xr);

        if (permuted)
            fused_edge<1><<<N_NODES, 64, 0, stream>>>(xl, xr, eap, ea, perm, offs, srcp,
                                                      we_, att_, bias_, gates, h, hact, layer);
        else
            fused_edge<0><<<N_NODES, 64, 0, stream>>>(xl, xr, eap, ea, perm, offs, srcp,
                                                      we_, att_, bias_, gates, h, hact, layer);
    }
}